// Round 1
// baseline (513.432 us; speedup 1.0000x reference)
//
#include <hip/hip_runtime.h>

// TTRFluxLayer: phi(q),phi(k) -> chunked causal+anticausal linear attention.
// B=1,H=24,N=4096,D=128,F=256,CHUNK=128. Output fp32 (B,H,N,D).
// Strategy: fp16 MFMA (16x16x32) everywhere, fp32 accum.
//   k0 prep:  w1,w2 fp32->fp16
//   k1 phi:   fused GEMM1+SiLU+GEMM2 per 64-row block -> qp,kp (fp16)
//   k2 S:     per-chunk S_T[d][f] = sum_s v[s][d]*kp[s][f]  (fp16 out)
//   k3 pfx:   exclusive prefix (fwd) + exclusive suffix (rev) over 32 chunks
//   k4 scan:  P=qp.kp^T once; out[i] = (qWf + (P.tril)v)/(i+1) + (qWr + (P.triu)v)/(N-i)
// ws layout (bytes): w1h 64K | w2h 128K | qp 48M | kp 48M | S 48M | Wf 48M | Wr 48M  (~252 MB)

typedef __attribute__((ext_vector_type(8))) _Float16 f16x8;
typedef __attribute__((ext_vector_type(4))) float f32x4;

#define MFMA16(a, b, c) __builtin_amdgcn_mfma_f32_16x16x32_f16((a), (b), (c), 0, 0, 0)

constexpr int BH   = 24;
constexpr int NSEQ = 4096;
constexpr int DD   = 128;
constexpr int FF   = 256;
constexpr int CHK  = 128;
constexpr int NC   = NSEQ / CHK;     // 32
constexpr int NROWS = BH * NSEQ;     // 98304

// ---------------- k0: weight convert ----------------
__global__ void prep_kernel(const float* __restrict__ w1, const float* __restrict__ w2,
                            _Float16* __restrict__ w1h, _Float16* __restrict__ w2h) {
  int i = blockIdx.x * 256 + threadIdx.x;
  if (i < FF * DD) w1h[i] = (_Float16)w1[i];
  if (i < FF * FF) w2h[i] = (_Float16)w2[i];
}

// ---------------- k1: phi (fused 2-GEMM + SiLU) ----------------
// block = 64 rows of q (blocks 0..1535) or k (1536..3071). 256 threads, 4 waves.
// wave grid 2(M)x2(Fhalf); wave tile 32x128.
__global__ void phi_kernel(const float* __restrict__ q, const float* __restrict__ k,
                           const float* __restrict__ b1, const float* __restrict__ b2,
                           const _Float16* __restrict__ w1h, const _Float16* __restrict__ w2h,
                           _Float16* __restrict__ qp, _Float16* __restrict__ kp) {
  __shared__ __align__(16) _Float16 xs[64][136];  // x tile (pad 8: 2-way banks only)
  __shared__ __align__(16) _Float16 hs[64][264];  // h tile
  int blk = blockIdx.x;
  const float* src;
  _Float16* dst;
  int rb;
  if (blk < NROWS / 64) { src = q; dst = qp; rb = blk * 64; }
  else                  { src = k; dst = kp; rb = (blk - NROWS / 64) * 64; }
  int tid = threadIdx.x;
  for (int i = tid; i < 64 * DD; i += 256) {
    int r = i >> 7, c = i & 127;
    xs[r][c] = (_Float16)src[(size_t)(rb + r) * DD + c];
  }
  __syncthreads();
  int lane = tid & 63, wv = tid >> 6;
  int wm = wv & 1, wn = wv >> 1;
  int lr = lane & 15, lq = lane >> 4;

  // GEMM1: h[64][256] = silu(x @ w1^T + b1), K=128
  f32x4 acc[2][8] = {};
#pragma unroll
  for (int ks = 0; ks < 4; ++ks) {
    f16x8 av[2];
#pragma unroll
    for (int im = 0; im < 2; ++im)
      av[im] = *(const f16x8*)&xs[wm * 32 + im * 16 + lr][ks * 32 + lq * 8];
#pragma unroll
    for (int fn = 0; fn < 8; ++fn) {
      int f = wn * 128 + fn * 16 + lr;
      f16x8 bv = *(const f16x8*)&w1h[f * DD + ks * 32 + lq * 8];
#pragma unroll
      for (int im = 0; im < 2; ++im) acc[im][fn] = MFMA16(av[im], bv, acc[im][fn]);
    }
  }
#pragma unroll
  for (int im = 0; im < 2; ++im)
#pragma unroll
    for (int fn = 0; fn < 8; ++fn) {
      int f = wn * 128 + fn * 16 + lr;
      float bb = b1[f];
      int r0 = wm * 32 + im * 16 + lq * 4;
#pragma unroll
      for (int r = 0; r < 4; ++r) {
        float xv = acc[im][fn][r] + bb;
        float sv = xv / (1.0f + __expf(-xv));  // SiLU
        hs[r0 + r][f] = (_Float16)sv;
      }
    }
  __syncthreads();

  // GEMM2: out[64][256] = h @ w2^T + b2, K=256
  f32x4 ac2[2][8] = {};
#pragma unroll
  for (int ks = 0; ks < 8; ++ks) {
    f16x8 av[2];
#pragma unroll
    for (int im = 0; im < 2; ++im)
      av[im] = *(const f16x8*)&hs[wm * 32 + im * 16 + lr][ks * 32 + lq * 8];
#pragma unroll
    for (int fn = 0; fn < 8; ++fn) {
      int g = wn * 128 + fn * 16 + lr;
      f16x8 bv = *(const f16x8*)&w2h[g * FF + ks * 32 + lq * 8];
#pragma unroll
      for (int im = 0; im < 2; ++im) ac2[im][fn] = MFMA16(av[im], bv, ac2[im][fn]);
    }
  }
#pragma unroll
  for (int im = 0; im < 2; ++im)
#pragma unroll
    for (int fn = 0; fn < 8; ++fn) {
      int g = wn * 128 + fn * 16 + lr;
      float bb = b2[g];
      int r0 = wm * 32 + im * 16 + lq * 4;
#pragma unroll
      for (int r = 0; r < 4; ++r)
        dst[(size_t)(rb + r0 + r) * FF + g] = (_Float16)(ac2[im][fn][r] + bb);
    }
}

// ---------------- k2: per-chunk S_T[d][f] = sum_s v[s][d] kp[s][f] ----------------
// grid: bh(24) x c(32) x dh(2) x fh(2). block out = 64(d) x 128(f). waves 2x2, tile 32x64.
__global__ void s_kernel(const float* __restrict__ v, const _Float16* __restrict__ kp,
                         _Float16* __restrict__ S) {
  __shared__ __align__(16) _Float16 vt[64][136];   // v^T  [d][s]
  __shared__ __align__(16) _Float16 kt[128][136];  // kp^T [f][s]
  int b = blockIdx.x;
  int fh = b & 1, dh = (b >> 1) & 1, c = (b >> 2) & 31, bh = b >> 7;
  const float*    vc  = v  + ((size_t)bh * NSEQ + c * CHK) * DD;
  const _Float16* kpc = kp + ((size_t)bh * NSEQ + c * CHK) * FF;
  int tid = threadIdx.x;
  for (int i = tid; i < 128 * 64; i += 256) {
    int s = i >> 6, d = i & 63;
    vt[d][s] = (_Float16)vc[(size_t)s * DD + dh * 64 + d];
  }
  for (int i = tid; i < 128 * 128; i += 256) {
    int s = i >> 7, f = i & 127;
    kt[f][s] = kpc[(size_t)s * FF + fh * 128 + f];
  }
  __syncthreads();
  int lane = tid & 63, wv = tid >> 6, wm = wv & 1, wn = wv >> 1;
  int lr = lane & 15, lq = lane >> 4;
  f32x4 acc[2][4] = {};
#pragma unroll
  for (int ks = 0; ks < 4; ++ks) {
    f16x8 av[2];
#pragma unroll
    for (int im = 0; im < 2; ++im)
      av[im] = *(const f16x8*)&vt[wm * 32 + im * 16 + lr][ks * 32 + lq * 8];
#pragma unroll
    for (int j = 0; j < 4; ++j) {
      f16x8 bv = *(const f16x8*)&kt[wn * 64 + j * 16 + lr][ks * 32 + lq * 8];
#pragma unroll
      for (int im = 0; im < 2; ++im) acc[im][j] = MFMA16(av[im], bv, acc[im][j]);
    }
  }
  _Float16* Sp = S + ((size_t)bh * NC + c) * (size_t)(DD * FF);
#pragma unroll
  for (int im = 0; im < 2; ++im)
#pragma unroll
    for (int j = 0; j < 4; ++j) {
      int f = fh * 128 + wn * 64 + j * 16 + lr;
#pragma unroll
      for (int r = 0; r < 4; ++r) {
        int d = dh * 64 + wm * 32 + im * 16 + lq * 4 + r;
        Sp[(size_t)d * FF + f] = (_Float16)acc[im][j][r];
      }
    }
}

// ---------------- k3: prefix/suffix over chunks ----------------
__global__ void prefix_kernel(const _Float16* __restrict__ S, _Float16* __restrict__ Wf,
                              _Float16* __restrict__ Wr) {
  size_t idx = (size_t)blockIdx.x * 256 + threadIdx.x;  // bh*32768 + d*256 + f
  int bh = (int)(idx >> 15);
  int df = (int)(idx & 32767);
  size_t base = (size_t)bh * NC * 32768 + df;
  float vals[NC];
#pragma unroll
  for (int c = 0; c < NC; ++c) vals[c] = (float)S[base + (size_t)c * 32768];
  float run = 0.f;
#pragma unroll
  for (int c = 0; c < NC; ++c) { Wf[base + (size_t)c * 32768] = (_Float16)run; run += vals[c]; }
  run = 0.f;
#pragma unroll
  for (int c = NC - 1; c >= 0; --c) { Wr[base + (size_t)c * 32768] = (_Float16)run; run += vals[c]; }
}

// ---------------- k4: fused phase-2 scan ----------------
// grid: bh(24) x c(32) x ih(2). block out = 64(i) x 128(d). waves 2x2, tile 32x64.
__global__ void scan_kernel(const _Float16* __restrict__ qp, const _Float16* __restrict__ kp,
                            const float* __restrict__ v, const _Float16* __restrict__ Wf,
                            const _Float16* __restrict__ Wr, float* __restrict__ out) {
  __shared__ __align__(16) _Float16 vt[128][136];  // v^T [d][s]
  __shared__ __align__(16) _Float16 P[64][136];    // attn scores [i_local][s]
  int b = blockIdx.x;
  int ih = b & 1, c = (b >> 1) & 31, bh = b >> 6;
  const _Float16* qpc = qp + ((size_t)bh * NSEQ + c * CHK) * FF;
  const _Float16* kpc = kp + ((size_t)bh * NSEQ + c * CHK) * FF;
  const float*    vc  = v  + ((size_t)bh * NSEQ + c * CHK) * DD;
  int tid = threadIdx.x;
  for (int i = tid; i < CHK * DD; i += 256) {
    int s = i >> 7, d = i & 127;
    vt[d][s] = (_Float16)vc[i];
  }
  int lane = tid & 63, wv = tid >> 6, wm = wv & 1, wn = wv >> 1;
  int lr = lane & 15, lq = lane >> 4;

  // Phase A: P = qp_c . kp_c^T  (64 rows for this ih-half x 128 s), K=F=256
  f32x4 pacc[2][4] = {};
#pragma unroll
  for (int ks = 0; ks < 8; ++ks) {
    f16x8 av[2];
#pragma unroll
    for (int im = 0; im < 2; ++im)
      av[im] = *(const f16x8*)&qpc[(size_t)(ih * 64 + wm * 32 + im * 16 + lr) * FF + ks * 32 + lq * 8];
#pragma unroll
    for (int j = 0; j < 4; ++j) {
      f16x8 bv = *(const f16x8*)&kpc[(size_t)(wn * 64 + j * 16 + lr) * FF + ks * 32 + lq * 8];
#pragma unroll
      for (int im = 0; im < 2; ++im) pacc[im][j] = MFMA16(av[im], bv, pacc[im][j]);
    }
  }
#pragma unroll
  for (int im = 0; im < 2; ++im)
#pragma unroll
    for (int j = 0; j < 4; ++j)
#pragma unroll
      for (int r = 0; r < 4; ++r)
        P[wm * 32 + im * 16 + lq * 4 + r][wn * 64 + j * 16 + lr] = (_Float16)pacc[im][j][r];
  __syncthreads();

  // Phase B: inter (q.Wf, q.Wr) + intra (masked P . v)
  const _Float16* Wfc = Wf + ((size_t)bh * NC + c) * (size_t)(DD * FF);
  const _Float16* Wrc = Wr + ((size_t)bh * NC + c) * (size_t)(DD * FF);
  f32x4 af[2][4] = {}, ar[2][4] = {};
#pragma unroll
  for (int ks = 0; ks < 8; ++ks) {
    f16x8 av[2];
#pragma unroll
    for (int im = 0; im < 2; ++im)
      av[im] = *(const f16x8*)&qpc[(size_t)(ih * 64 + wm * 32 + im * 16 + lr) * FF + ks * 32 + lq * 8];
#pragma unroll
    for (int j = 0; j < 4; ++j) {
      int d = wn * 64 + j * 16 + lr;
      f16x8 bf = *(const f16x8*)&Wfc[(size_t)d * FF + ks * 32 + lq * 8];
      f16x8 br = *(const f16x8*)&Wrc[(size_t)d * FF + ks * 32 + lq * 8];
#pragma unroll
      for (int im = 0; im < 2; ++im) {
        af[im][j] = MFMA16(av[im], bf, af[im][j]);
        ar[im][j] = MFMA16(av[im], br, ar[im][j]);
      }
    }
  }
#pragma unroll
  for (int ks = 0; ks < 4; ++ks) {
#pragma unroll
    for (int im = 0; im < 2; ++im) {
      int irow = wm * 32 + im * 16 + lr;   // local P row
      int ichunk = ih * 64 + irow;         // chunk-local token index
      f16x8 p = *(const f16x8*)&P[irow][ks * 32 + lq * 8];
      f16x8 pf = p, pr = p;
#pragma unroll
      for (int jj = 0; jj < 8; ++jj) {
        int s = ks * 32 + lq * 8 + jj;
        pf[jj] = (s <= ichunk) ? p[jj] : (_Float16)0.0f;  // tril incl diag
        pr[jj] = (s >= ichunk) ? p[jj] : (_Float16)0.0f;  // triu incl diag
      }
#pragma unroll
      for (int j = 0; j < 4; ++j) {
        f16x8 bv = *(const f16x8*)&vt[wn * 64 + j * 16 + lr][ks * 32 + lq * 8];
        af[im][j] = MFMA16(pf, bv, af[im][j]);
        ar[im][j] = MFMA16(pr, bv, ar[im][j]);
      }
    }
  }
  // Epilogue: out[i] = fwd/(gi+1) + rev/(N-gi)
  float* oc = out + ((size_t)bh * NSEQ + c * CHK) * DD;
#pragma unroll
  for (int im = 0; im < 2; ++im)
#pragma unroll
    for (int j = 0; j < 4; ++j) {
      int d = wn * 64 + j * 16 + lr;
#pragma unroll
      for (int r = 0; r < 4; ++r) {
        int il = ih * 64 + wm * 32 + im * 16 + lq * 4 + r;
        int gi = c * CHK + il;
        float val = af[im][j][r] / (float)(gi + 1) + ar[im][j][r] / (float)(NSEQ - gi);
        oc[(size_t)il * DD + d] = val;
      }
    }
}

// ---------------- launcher ----------------
extern "C" void kernel_launch(void* const* d_in, const int* in_sizes, int n_in,
                              void* d_out, int out_size, void* d_ws, size_t ws_size,
                              hipStream_t stream) {
  const float* q  = (const float*)d_in[0];
  const float* k  = (const float*)d_in[1];
  const float* v  = (const float*)d_in[2];
  const float* w1 = (const float*)d_in[3];
  const float* b1 = (const float*)d_in[4];
  const float* w2 = (const float*)d_in[5];
  const float* b2 = (const float*)d_in[6];
  float* out = (float*)d_out;

  char* ws = (char*)d_ws;
  const size_t SZ = 50331648ull;  // 24*4096*256 * 2B (also 24*32*128*256*2B)
  _Float16* w1h = (_Float16*)(ws);
  _Float16* w2h = (_Float16*)(ws + 65536);
  _Float16* qp  = (_Float16*)(ws + 196608);
  _Float16* kp  = (_Float16*)(ws + 196608 + SZ);
  _Float16* S   = (_Float16*)(ws + 196608 + 2 * SZ);
  _Float16* Wf  = (_Float16*)(ws + 196608 + 3 * SZ);
  _Float16* Wr  = (_Float16*)(ws + 196608 + 4 * SZ);  // total ~252 MB

  prep_kernel<<<dim3(256), dim3(256), 0, stream>>>(w1, w2, w1h, w2h);
  phi_kernel<<<dim3(2 * NROWS / 64), dim3(256), 0, stream>>>(q, k, b1, b2, w1h, w2h, qp, kp);
  s_kernel<<<dim3(BH * NC * 4), dim3(256), 0, stream>>>(v, kp, S);
  prefix_kernel<<<dim3(BH * DD * FF / 256), dim3(256), 0, stream>>>(S, Wf, Wr);
  scan_kernel<<<dim3(BH * NC * 2), dim3(256), 0, stream>>>(qp, kp, v, Wf, Wr, out);
}

// Round 2
// 482.875 us; speedup vs baseline: 1.0633x; 1.0633x over previous
//
#include <hip/hip_runtime.h>

// TTRFluxLayer: phi(q),phi(k) -> chunked causal+anticausal linear attention.
// B=1,H=24,N=4096,D=128,F=256,CHUNK=128. Output fp32 (B,H,N,D).
// R2: register-batched B-operand loads (latency was the killer: MfmaUtil 7.8%).
//   phi:  GEMM1 weights fully pre-batched (32 frags); GEMM2 in two fn-halves,
//         half1 loads interleaved into half0 K-loop. x staged as float4.
//   scan: qp A-frags batched once (shared by QK^T and q.W phases); kp B-frags
//         batched; inter-phase W loads prefetched per d-group and interleaved
//         with intra-phase masked-P MFMAs.
// ws layout (bytes): w1h 64K | w2h 128K | qp 48M | kp 48M | S 48M | Wf 48M | Wr 48M

typedef __attribute__((ext_vector_type(8))) _Float16 f16x8;
typedef __attribute__((ext_vector_type(4))) _Float16 f16x4;
typedef __attribute__((ext_vector_type(4))) float f32x4;

#define MFMA16(a, b, c) __builtin_amdgcn_mfma_f32_16x16x32_f16((a), (b), (c), 0, 0, 0)

constexpr int BH   = 24;
constexpr int NSEQ = 4096;
constexpr int DD   = 128;
constexpr int FF   = 256;
constexpr int CHK  = 128;
constexpr int NC   = NSEQ / CHK;     // 32
constexpr int NROWS = BH * NSEQ;     // 98304

// ---------------- k0: weight convert ----------------
__global__ void prep_kernel(const float* __restrict__ w1, const float* __restrict__ w2,
                            _Float16* __restrict__ w1h, _Float16* __restrict__ w2h) {
  int i = blockIdx.x * 256 + threadIdx.x;
  if (i < FF * DD) w1h[i] = (_Float16)w1[i];
  if (i < FF * FF) w2h[i] = (_Float16)w2[i];
}

// ---------------- k1: phi (fused 2-GEMM + SiLU) ----------------
__global__ __launch_bounds__(256, 2)
void phi_kernel(const float* __restrict__ q, const float* __restrict__ k,
                const float* __restrict__ b1, const float* __restrict__ b2,
                const _Float16* __restrict__ w1h, const _Float16* __restrict__ w2h,
                _Float16* __restrict__ qp, _Float16* __restrict__ kp) {
  __shared__ __align__(16) _Float16 xs[64][136];
  __shared__ __align__(16) _Float16 hs[64][264];
  int blk = blockIdx.x;
  const float* src;
  _Float16* dst;
  int rb;
  if (blk < NROWS / 64) { src = q; dst = qp; rb = blk * 64; }
  else                  { src = k; dst = kp; rb = (blk - NROWS / 64) * 64; }
  int tid = threadIdx.x;
  int lane = tid & 63, wv = tid >> 6;
  int wm = wv & 1, wn = wv >> 1;
  int lr = lane & 15, lq = lane >> 4;

  // --- batch-issue ALL GEMM1 weight frags (latency hides behind x staging) ---
  f16x8 b1r[4][8];
#pragma unroll
  for (int ks = 0; ks < 4; ++ks)
#pragma unroll
    for (int fn = 0; fn < 8; ++fn)
      b1r[ks][fn] = *(const f16x8*)&w1h[(wn * 128 + fn * 16 + lr) * DD + ks * 32 + lq * 8];

  // --- stage x tile as float4 ---
#pragma unroll
  for (int i = 0; i < 8; ++i) {
    int flat = i * 1024 + tid * 4;
    int r = flat >> 7, c = flat & 127;
    float4 xv = *(const float4*)&src[(size_t)(rb + r) * DD + c];
    f16x4 hv = {(_Float16)xv.x, (_Float16)xv.y, (_Float16)xv.z, (_Float16)xv.w};
    *(f16x4*)&xs[r][c] = hv;
  }
  __syncthreads();

  // --- GEMM1: h = silu(x @ w1^T + b1), K=128, weights in regs ---
  f32x4 acc[2][8] = {};
#pragma unroll
  for (int ks = 0; ks < 4; ++ks) {
    f16x8 av[2];
#pragma unroll
    for (int im = 0; im < 2; ++im)
      av[im] = *(const f16x8*)&xs[wm * 32 + im * 16 + lr][ks * 32 + lq * 8];
#pragma unroll
    for (int fn = 0; fn < 8; ++fn)
#pragma unroll
      for (int im = 0; im < 2; ++im) acc[im][fn] = MFMA16(av[im], b1r[ks][fn], acc[im][fn]);
  }

  // --- batch-issue GEMM2 half0 weight frags (latency hides behind SiLU+stores+barrier) ---
  f16x8 b2r[8][4];
#pragma unroll
  for (int ks = 0; ks < 8; ++ks)
#pragma unroll
    for (int fn = 0; fn < 4; ++fn)
      b2r[ks][fn] = *(const f16x8*)&w2h[(wn * 128 + fn * 16 + lr) * FF + ks * 32 + lq * 8];

  // --- SiLU epilogue -> hs ---
#pragma unroll
  for (int im = 0; im < 2; ++im)
#pragma unroll
    for (int fn = 0; fn < 8; ++fn) {
      int f = wn * 128 + fn * 16 + lr;
      float bb = b1[f];
      int r0 = wm * 32 + im * 16 + lq * 4;
#pragma unroll
      for (int r = 0; r < 4; ++r) {
        float xv = acc[im][fn][r] + bb;
        float sv = xv / (1.0f + __expf(-xv));
        hs[r0 + r][f] = (_Float16)sv;
      }
    }
  __syncthreads();

  // --- GEMM2 half0 (out cols wn*128 + [0,64)); interleave half1 loads ---
  f16x8 b3r[8][4];
  f32x4 ac2[2][4] = {};
#pragma unroll
  for (int ks = 0; ks < 8; ++ks) {
    f16x8 av[2];
#pragma unroll
    for (int im = 0; im < 2; ++im)
      av[im] = *(const f16x8*)&hs[wm * 32 + im * 16 + lr][ks * 32 + lq * 8];
#pragma unroll
    for (int fn = 0; fn < 4; ++fn)
#pragma unroll
      for (int im = 0; im < 2; ++im) ac2[im][fn] = MFMA16(av[im], b2r[ks][fn], ac2[im][fn]);
    // prefetch half1 frags for this ks (b2r[ks] now dead)
#pragma unroll
    for (int fn = 0; fn < 4; ++fn)
      b3r[ks][fn] = *(const f16x8*)&w2h[(wn * 128 + (4 + fn) * 16 + lr) * FF + ks * 32 + lq * 8];
  }
  // store half0 (covers half1 load latency)
#pragma unroll
  for (int im = 0; im < 2; ++im)
#pragma unroll
    for (int fn = 0; fn < 4; ++fn) {
      int g = wn * 128 + fn * 16 + lr;
      float bb = b2[g];
      int r0 = wm * 32 + im * 16 + lq * 4;
#pragma unroll
      for (int r = 0; r < 4; ++r)
        dst[(size_t)(rb + r0 + r) * FF + g] = (_Float16)(ac2[im][fn][r] + bb);
    }

  // --- GEMM2 half1 ---
  f32x4 ac3[2][4] = {};
#pragma unroll
  for (int ks = 0; ks < 8; ++ks) {
    f16x8 av[2];
#pragma unroll
    for (int im = 0; im < 2; ++im)
      av[im] = *(const f16x8*)&hs[wm * 32 + im * 16 + lr][ks * 32 + lq * 8];
#pragma unroll
    for (int fn = 0; fn < 4; ++fn)
#pragma unroll
      for (int im = 0; im < 2; ++im) ac3[im][fn] = MFMA16(av[im], b3r[ks][fn], ac3[im][fn]);
  }
#pragma unroll
  for (int im = 0; im < 2; ++im)
#pragma unroll
    for (int fn = 0; fn < 4; ++fn) {
      int g = wn * 128 + (4 + fn) * 16 + lr;
      float bb = b2[g];
      int r0 = wm * 32 + im * 16 + lq * 4;
#pragma unroll
      for (int r = 0; r < 4; ++r)
        dst[(size_t)(rb + r0 + r) * FF + g] = (_Float16)(ac3[im][fn][r] + bb);
    }
}

// ---------------- k2: per-chunk S_T[d][f] = sum_s v[s][d] kp[s][f] ----------------
__global__ void s_kernel(const float* __restrict__ v, const _Float16* __restrict__ kp,
                         _Float16* __restrict__ S) {
  __shared__ __align__(16) _Float16 vt[64][136];
  __shared__ __align__(16) _Float16 kt[128][136];
  int b = blockIdx.x;
  int fh = b & 1, dh = (b >> 1) & 1, c = (b >> 2) & 31, bh = b >> 7;
  const float*    vc  = v  + ((size_t)bh * NSEQ + c * CHK) * DD;
  const _Float16* kpc = kp + ((size_t)bh * NSEQ + c * CHK) * FF;
  int tid = threadIdx.x;
  for (int i = tid; i < 128 * 64; i += 256) {
    int s = i >> 6, d = i & 63;
    vt[d][s] = (_Float16)vc[(size_t)s * DD + dh * 64 + d];
  }
  for (int i = tid; i < 128 * 128; i += 256) {
    int s = i >> 7, f = i & 127;
    kt[f][s] = kpc[(size_t)s * FF + fh * 128 + f];
  }
  __syncthreads();
  int lane = tid & 63, wv = tid >> 6, wm = wv & 1, wn = wv >> 1;
  int lr = lane & 15, lq = lane >> 4;
  f32x4 acc[2][4] = {};
#pragma unroll
  for (int ks = 0; ks < 4; ++ks) {
    f16x8 av[2];
#pragma unroll
    for (int im = 0; im < 2; ++im)
      av[im] = *(const f16x8*)&vt[wm * 32 + im * 16 + lr][ks * 32 + lq * 8];
#pragma unroll
    for (int j = 0; j < 4; ++j) {
      f16x8 bv = *(const f16x8*)&kt[wn * 64 + j * 16 + lr][ks * 32 + lq * 8];
#pragma unroll
      for (int im = 0; im < 2; ++im) acc[im][j] = MFMA16(av[im], bv, acc[im][j]);
    }
  }
  _Float16* Sp = S + ((size_t)bh * NC + c) * (size_t)(DD * FF);
#pragma unroll
  for (int im = 0; im < 2; ++im)
#pragma unroll
    for (int j = 0; j < 4; ++j) {
      int f = fh * 128 + wn * 64 + j * 16 + lr;
#pragma unroll
      for (int r = 0; r < 4; ++r) {
        int d = dh * 64 + wm * 32 + im * 16 + lq * 4 + r;
        Sp[(size_t)d * FF + f] = (_Float16)acc[im][j][r];
      }
    }
}

// ---------------- k3: prefix/suffix over chunks ----------------
__global__ void prefix_kernel(const _Float16* __restrict__ S, _Float16* __restrict__ Wf,
                              _Float16* __restrict__ Wr) {
  size_t idx = (size_t)blockIdx.x * 256 + threadIdx.x;
  int bh = (int)(idx >> 15);
  int df = (int)(idx & 32767);
  size_t base = (size_t)bh * NC * 32768 + df;
  float vals[NC];
#pragma unroll
  for (int c = 0; c < NC; ++c) vals[c] = (float)S[base + (size_t)c * 32768];
  float run = 0.f;
#pragma unroll
  for (int c = 0; c < NC; ++c) { Wf[base + (size_t)c * 32768] = (_Float16)run; run += vals[c]; }
  run = 0.f;
#pragma unroll
  for (int c = NC - 1; c >= 0; --c) { Wr[base + (size_t)c * 32768] = (_Float16)run; run += vals[c]; }
}

// ---------------- k4: fused phase-2 scan ----------------
__global__ __launch_bounds__(256, 2)
void scan_kernel(const _Float16* __restrict__ qp, const _Float16* __restrict__ kp,
                 const float* __restrict__ v, const _Float16* __restrict__ Wf,
                 const _Float16* __restrict__ Wr, float* __restrict__ out) {
  __shared__ __align__(16) _Float16 vt[128][136];
  __shared__ __align__(16) _Float16 P[64][136];
  int b = blockIdx.x;
  int ih = b & 1, c = (b >> 1) & 31, bh = b >> 6;
  const _Float16* qpc = qp + ((size_t)bh * NSEQ + c * CHK) * FF;
  const _Float16* kpc = kp + ((size_t)bh * NSEQ + c * CHK) * FF;
  const float*    vc  = v  + ((size_t)bh * NSEQ + c * CHK) * DD;
  int tid = threadIdx.x;
  int lane = tid & 63, wv = tid >> 6, wm = wv & 1, wn = wv >> 1;
  int lr = lane & 15, lq = lane >> 4;

  // --- batch A-frags (qp rows): reused by QK^T AND q.W phases ---
  f16x8 aq[2][8];
#pragma unroll
  for (int im = 0; im < 2; ++im)
#pragma unroll
    for (int ks = 0; ks < 8; ++ks)
      aq[im][ks] = *(const f16x8*)&qpc[(size_t)(ih * 64 + wm * 32 + im * 16 + lr) * FF + ks * 32 + lq * 8];

  // --- batch B-frags for QK^T (kp rows) ---
  f16x8 bk[8][4];
#pragma unroll
  for (int ks = 0; ks < 8; ++ks)
#pragma unroll
    for (int j = 0; j < 4; ++j)
      bk[ks][j] = *(const f16x8*)&kpc[(size_t)(wn * 64 + j * 16 + lr) * FF + ks * 32 + lq * 8];

  // --- stage v^T (covers the batch-load latency above) ---
  for (int i = tid; i < CHK * DD; i += 256) {
    int s = i >> 7, d = i & 127;
    vt[d][s] = (_Float16)vc[i];
  }

  // --- Phase A: P = qp_c . kp_c^T ---
  f32x4 pacc[2][4] = {};
#pragma unroll
  for (int ks = 0; ks < 8; ++ks)
#pragma unroll
    for (int j = 0; j < 4; ++j)
#pragma unroll
      for (int im = 0; im < 2; ++im) pacc[im][j] = MFMA16(aq[im][ks], bk[ks][j], pacc[im][j]);
#pragma unroll
  for (int im = 0; im < 2; ++im)
#pragma unroll
    for (int j = 0; j < 4; ++j)
#pragma unroll
      for (int r = 0; r < 4; ++r)
        P[wm * 32 + im * 16 + lq * 4 + r][wn * 64 + j * 16 + lr] = (_Float16)pacc[im][j][r];

  const _Float16* Wfc = Wf + ((size_t)bh * NC + c) * (size_t)(DD * FF);
  const _Float16* Wrc = Wr + ((size_t)bh * NC + c) * (size_t)(DD * FF);

  // prefetch inter-phase W frags for d-group j=0
  f16x8 bf[8], br[8];
#pragma unroll
  for (int ks = 0; ks < 8; ++ks) {
    int d = wn * 64 + 0 * 16 + lr;
    bf[ks] = *(const f16x8*)&Wfc[(size_t)d * FF + ks * 32 + lq * 8];
    br[ks] = *(const f16x8*)&Wrc[(size_t)d * FF + ks * 32 + lq * 8];
  }
  __syncthreads();

  // --- Phase B: interleave inter (q.W) d-groups with intra (masked P.v) k-steps ---
  f32x4 af[2][4] = {}, ar[2][4] = {};
#pragma unroll
  for (int j = 0; j < 4; ++j) {
    // inter MFMAs for d-group j (W frags already in regs)
#pragma unroll
    for (int ks = 0; ks < 8; ++ks)
#pragma unroll
      for (int im = 0; im < 2; ++im) {
        af[im][j] = MFMA16(aq[im][ks], bf[ks], af[im][j]);
        ar[im][j] = MFMA16(aq[im][ks], br[ks], ar[im][j]);
      }
    // prefetch W frags for d-group j+1 (regs just freed)
    if (j < 3) {
#pragma unroll
      for (int ks = 0; ks < 8; ++ks) {
        int d = wn * 64 + (j + 1) * 16 + lr;
        bf[ks] = *(const f16x8*)&Wfc[(size_t)d * FF + ks * 32 + lq * 8];
        br[ks] = *(const f16x8*)&Wrc[(size_t)d * FF + ks * 32 + lq * 8];
      }
    }
    // intra k-step ks=j (covers W prefetch latency; LDS-only operands)
    {
      int ks = j;
#pragma unroll
      for (int im = 0; im < 2; ++im) {
        int irow = wm * 32 + im * 16 + lr;
        int ichunk = ih * 64 + irow;
        f16x8 p = *(const f16x8*)&P[irow][ks * 32 + lq * 8];
        f16x8 pf = p, pr = p;
#pragma unroll
        for (int jj = 0; jj < 8; ++jj) {
          int s = ks * 32 + lq * 8 + jj;
          pf[jj] = (s <= ichunk) ? p[jj] : (_Float16)0.0f;
          pr[jj] = (s >= ichunk) ? p[jj] : (_Float16)0.0f;
        }
#pragma unroll
        for (int jd = 0; jd < 4; ++jd) {
          f16x8 bv = *(const f16x8*)&vt[wn * 64 + jd * 16 + lr][ks * 32 + lq * 8];
          af[im][jd] = MFMA16(pf, bv, af[im][jd]);
          ar[im][jd] = MFMA16(pr, bv, ar[im][jd]);
        }
      }
    }
  }

  // --- epilogue ---
  float* oc = out + ((size_t)bh * NSEQ + c * CHK) * DD;
#pragma unroll
  for (int im = 0; im < 2; ++im)
#pragma unroll
    for (int j = 0; j < 4; ++j) {
      int d = wn * 64 + j * 16 + lr;
#pragma unroll
      for (int r = 0; r < 4; ++r) {
        int il = ih * 64 + wm * 32 + im * 16 + lq * 4 + r;
        int gi = c * CHK + il;
        float val = af[im][j][r] / (float)(gi + 1) + ar[im][j][r] / (float)(NSEQ - gi);
        oc[(size_t)il * DD + d] = val;
      }
    }
}

// ---------------- launcher ----------------
extern "C" void kernel_launch(void* const* d_in, const int* in_sizes, int n_in,
                              void* d_out, int out_size, void* d_ws, size_t ws_size,
                              hipStream_t stream) {
  const float* q  = (const float*)d_in[0];
  const float* k  = (const float*)d_in[1];
  const float* v  = (const float*)d_in[2];
  const float* w1 = (const float*)d_in[3];
  const float* b1 = (const float*)d_in[4];
  const float* w2 = (const float*)d_in[5];
  const float* b2 = (const float*)d_in[6];
  float* out = (float*)d_out;

  char* ws = (char*)d_ws;
  const size_t SZ = 50331648ull;
  _Float16* w1h = (_Float16*)(ws);
  _Float16* w2h = (_Float16*)(ws + 65536);
  _Float16* qp  = (_Float16*)(ws + 196608);
  _Float16* kp  = (_Float16*)(ws + 196608 + SZ);
  _Float16* S   = (_Float16*)(ws + 196608 + 2 * SZ);
  _Float16* Wf  = (_Float16*)(ws + 196608 + 3 * SZ);
  _Float16* Wr  = (_Float16*)(ws + 196608 + 4 * SZ);

  prep_kernel<<<dim3(256), dim3(256), 0, stream>>>(w1, w2, w1h, w2h);
  phi_kernel<<<dim3(2 * NROWS / 64), dim3(256), 0, stream>>>(q, k, b1, b2, w1h, w2h, qp, kp);
  s_kernel<<<dim3(BH * NC * 4), dim3(256), 0, stream>>>(v, kp, S);
  prefix_kernel<<<dim3(BH * DD * FF / 256), dim3(256), 0, stream>>>(S, Wf, Wr);
  scan_kernel<<<dim3(BH * NC * 2), dim3(256), 0, stream>>>(qp, kp, v, Wf, Wr, out);
}

// Round 3
// 416.017 us; speedup vs baseline: 1.2342x; 1.1607x over previous
//
#include <hip/hip_runtime.h>

// TTRFluxLayer R3: LDS-resident operands (R2's register batching spilled).
// k0 prep: w1,w2 -> fp16.   k0b vt: v -> vT fp16 [bh][d][s] (LDS transpose).
// k1 phi: 128-row blocks, 512thr, weights staged in LDS (union, 134KB);
//         writes qp, kp (row-major) and kpT [bh][f][s].
// k2 s:   S^T[d][f] per chunk from vT/kpT tiles (pure b128 staging).
// k3 pfx: exclusive prefix->Wf (aliases dead kpT... no: separate region),
//         exclusive suffix written IN-PLACE over S (=Wr).
// k4 scan: full chunk per block (512thr); aq regs; bk dbuf; W prefetch 1 ahead.
// ws: w1h 64K | w2h 128K | qp 48M | kp 48M | kpT/Wf 48M | S/Wr 48M | vT 24M

typedef __attribute__((ext_vector_type(8))) _Float16 f16x8;
typedef __attribute__((ext_vector_type(4))) _Float16 f16x4;
typedef __attribute__((ext_vector_type(4))) float f32x4;

#define MFMA16(a, b, c) __builtin_amdgcn_mfma_f32_16x16x32_f16((a), (b), (c), 0, 0, 0)

constexpr int BH   = 24;
constexpr int NSEQ = 4096;
constexpr int DD   = 128;
constexpr int FF   = 256;
constexpr int CHK  = 128;
constexpr int NC   = NSEQ / CHK;     // 32
constexpr int NROWS = BH * NSEQ;     // 98304

// ---------------- k0: weight convert ----------------
__global__ void prep_kernel(const float* __restrict__ w1, const float* __restrict__ w2,
                            _Float16* __restrict__ w1h, _Float16* __restrict__ w2h) {
  int i = blockIdx.x * 256 + threadIdx.x;
  if (i < FF * DD) w1h[i] = (_Float16)w1[i];
  if (i < FF * FF) w2h[i] = (_Float16)w2[i];
}

// ---------------- k0b: v -> vT fp16 [bh][d][s] ----------------
__global__ void vt_kernel(const float* __restrict__ v, _Float16* __restrict__ vT) {
  __shared__ __align__(16) _Float16 lt[128][136];
  int blk = blockIdx.x;
  int c = blk & 31, bh = blk >> 5;
  const float* vc = v + ((size_t)bh * NSEQ + c * CHK) * DD;
  int tid = threadIdx.x;
#pragma unroll
  for (int it = 0; it < 16; ++it) {
    int flat = it * 1024 + tid * 4;  // 128s x 128d
    int s = flat >> 7, d0 = flat & 127;
    float4 xv = *(const float4*)&vc[(size_t)s * DD + d0];
    lt[d0 + 0][s] = (_Float16)xv.x;
    lt[d0 + 1][s] = (_Float16)xv.y;
    lt[d0 + 2][s] = (_Float16)xv.z;
    lt[d0 + 3][s] = (_Float16)xv.w;
  }
  __syncthreads();
#pragma unroll
  for (int it = 0; it < 8; ++it) {
    int flat = it * 256 + tid;  // 128d x 16 s-groups
    int d = flat >> 4, sg = flat & 15;
    *(f16x8*)&vT[((size_t)bh * DD + d) * NSEQ + c * CHK + sg * 8] =
        *(const f16x8*)&lt[d][sg * 8];
  }
}

// ---------------- k1: phi (fused 2-GEMM + SiLU, LDS weights) ----------------
__global__ __launch_bounds__(512, 2)
void phi_kernel(const float* __restrict__ q, const float* __restrict__ k,
                const float* __restrict__ b1, const float* __restrict__ b2,
                const _Float16* __restrict__ w1h, const _Float16* __restrict__ w2h,
                _Float16* __restrict__ qp, _Float16* __restrict__ kp,
                _Float16* __restrict__ kpT) {
  __shared__ __align__(16) char smem[137216];
  _Float16 (*xs)[136]  = (_Float16(*)[136])smem;             // [128][136] phase1
  _Float16 (*w1s)[136] = (_Float16(*)[136])(smem + 34816);   // [256][136] phase1
  _Float16 (*hs)[264]  = (_Float16(*)[264])smem;             // [128][264] phase2+
  _Float16 (*w2s)[136] = (_Float16(*)[136])(smem + 67584);   // [256][136] K-panel
  int blk = blockIdx.x;
  const float* src;
  _Float16* dst;
  bool isk;
  int rb;
  if (blk < NROWS / 128) { src = q; dst = qp; rb = blk * 128; isk = false; }
  else                   { src = k; dst = kp; rb = (blk - NROWS / 128) * 128; isk = true; }
  int tid = threadIdx.x;
  int lane = tid & 63, wv = tid >> 6, lr = lane & 15, lq = lane >> 4;

  // stage w1 (256x128) and x (128x128 f32->f16)
#pragma unroll
  for (int it = 0; it < 8; ++it) {
    int flat = it * 512 + tid;
    int f = flat >> 4, cg = flat & 15;
    *(f16x8*)&w1s[f][cg * 8] = *(const f16x8*)&w1h[f * DD + cg * 8];
  }
#pragma unroll
  for (int it = 0; it < 8; ++it) {
    int flat = it * 512 + tid;
    int r = flat >> 5, dg = flat & 31;
    float4 xv = *(const float4*)&src[(size_t)(rb + r) * DD + dg * 4];
    f16x4 hv = {(_Float16)xv.x, (_Float16)xv.y, (_Float16)xv.z, (_Float16)xv.w};
    *(f16x4*)&xs[r][dg * 4] = hv;
  }
  __syncthreads();

  // GEMM1: wave tile 64x64 over 128x256
  int wm1 = wv & 1, wn1 = wv >> 1;
  f32x4 acc[4][4] = {};
#pragma unroll
  for (int ks = 0; ks < 4; ++ks) {
    f16x8 av[4];
#pragma unroll
    for (int im = 0; im < 4; ++im)
      av[im] = *(const f16x8*)&xs[wm1 * 64 + im * 16 + lr][ks * 32 + lq * 8];
#pragma unroll
    for (int fn = 0; fn < 4; ++fn) {
      f16x8 bv = *(const f16x8*)&w1s[wn1 * 64 + fn * 16 + lr][ks * 32 + lq * 8];
#pragma unroll
      for (int im = 0; im < 4; ++im) acc[im][fn] = MFMA16(av[im], bv, acc[im][fn]);
    }
  }
  __syncthreads();  // xs/w1s dead

  // stage w2 K-panel 0 + write hs = silu(acc+b1)
#pragma unroll
  for (int it = 0; it < 8; ++it) {
    int flat = it * 512 + tid;
    int g = flat >> 4, cg = flat & 15;
    *(f16x8*)&w2s[g][cg * 8] = *(const f16x8*)&w2h[(size_t)g * FF + cg * 8];
  }
#pragma unroll
  for (int im = 0; im < 4; ++im)
#pragma unroll
    for (int fn = 0; fn < 4; ++fn) {
      int f = wn1 * 64 + fn * 16 + lr;
      float bb = b1[f];
      int r0 = wm1 * 64 + im * 16 + lq * 4;
#pragma unroll
      for (int r = 0; r < 4; ++r) {
        float xv = acc[im][fn][r] + bb;
        hs[r0 + r][f] = (_Float16)(xv / (1.0f + __expf(-xv)));
      }
    }
  __syncthreads();

  // GEMM2 K-panel 0
  int wmg = wv & 1, wng = wv >> 1;
  f32x4 ac2[4][4] = {};
#pragma unroll
  for (int ks = 0; ks < 4; ++ks) {
    f16x8 av[4];
#pragma unroll
    for (int im = 0; im < 4; ++im)
      av[im] = *(const f16x8*)&hs[wmg * 64 + im * 16 + lr][ks * 32 + lq * 8];
#pragma unroll
    for (int fn = 0; fn < 4; ++fn) {
      f16x8 bv = *(const f16x8*)&w2s[wng * 64 + fn * 16 + lr][ks * 32 + lq * 8];
#pragma unroll
      for (int im = 0; im < 4; ++im) ac2[im][fn] = MFMA16(av[im], bv, ac2[im][fn]);
    }
  }
  __syncthreads();  // panel0 consumed
#pragma unroll
  for (int it = 0; it < 8; ++it) {
    int flat = it * 512 + tid;
    int g = flat >> 4, cg = flat & 15;
    *(f16x8*)&w2s[g][cg * 8] = *(const f16x8*)&w2h[(size_t)g * FF + 128 + cg * 8];
  }
  __syncthreads();
#pragma unroll
  for (int ks = 0; ks < 4; ++ks) {
    f16x8 av[4];
#pragma unroll
    for (int im = 0; im < 4; ++im)
      av[im] = *(const f16x8*)&hs[wmg * 64 + im * 16 + lr][128 + ks * 32 + lq * 8];
#pragma unroll
    for (int fn = 0; fn < 4; ++fn) {
      f16x8 bv = *(const f16x8*)&w2s[wng * 64 + fn * 16 + lr][ks * 32 + lq * 8];
#pragma unroll
      for (int im = 0; im < 4; ++im) ac2[im][fn] = MFMA16(av[im], bv, ac2[im][fn]);
    }
  }

  // epilogue: qp/kp row-major; k also -> kpT[bh][f][s]
  int bh = rb >> 12, s0 = rb & 4095;
#pragma unroll
  for (int im = 0; im < 4; ++im)
#pragma unroll
    for (int fn = 0; fn < 4; ++fn) {
      int g = wng * 64 + fn * 16 + lr;
      float bb = b2[g];
      int r0 = wmg * 64 + im * 16 + lq * 4;
#pragma unroll
      for (int r = 0; r < 4; ++r) {
        _Float16 val = (_Float16)(ac2[im][fn][r] + bb);
        dst[(size_t)(rb + r0 + r) * FF + g] = val;
        if (isk) kpT[((size_t)bh * FF + g) * NSEQ + s0 + r0 + r] = val;
      }
    }
}

// ---------------- k2: S^T[d][f] per chunk ----------------
__global__ __launch_bounds__(512, 2)
void s_kernel(const _Float16* __restrict__ vT, const _Float16* __restrict__ kpT,
              _Float16* __restrict__ S) {
  __shared__ __align__(16) _Float16 vt[128][136];
  __shared__ __align__(16) _Float16 kt[256][136];
  int blk = blockIdx.x;
  int c = blk & 31, bh = blk >> 5;
  int tid = threadIdx.x;
#pragma unroll
  for (int it = 0; it < 4; ++it) {
    int flat = it * 512 + tid;
    int d = flat >> 4, sg = flat & 15;
    *(f16x8*)&vt[d][sg * 8] = *(const f16x8*)&vT[((size_t)bh * DD + d) * NSEQ + c * CHK + sg * 8];
  }
#pragma unroll
  for (int it = 0; it < 8; ++it) {
    int flat = it * 512 + tid;
    int f = flat >> 4, sg = flat & 15;
    *(f16x8*)&kt[f][sg * 8] = *(const f16x8*)&kpT[((size_t)bh * FF + f) * NSEQ + c * CHK + sg * 8];
  }
  __syncthreads();
  int lane = tid & 63, wv = tid >> 6, lr = lane & 15, lq = lane >> 4;
  int wmd = wv & 1, wnf = wv >> 1;
  f32x4 acc[4][4] = {};
#pragma unroll
  for (int ks = 0; ks < 4; ++ks) {
    f16x8 av[4];
#pragma unroll
    for (int im = 0; im < 4; ++im)
      av[im] = *(const f16x8*)&vt[wmd * 64 + im * 16 + lr][ks * 32 + lq * 8];
#pragma unroll
    for (int fn = 0; fn < 4; ++fn) {
      f16x8 bv = *(const f16x8*)&kt[wnf * 64 + fn * 16 + lr][ks * 32 + lq * 8];
#pragma unroll
      for (int im = 0; im < 4; ++im) acc[im][fn] = MFMA16(av[im], bv, acc[im][fn]);
    }
  }
  _Float16* Sp = S + ((size_t)bh * NC + c) * (size_t)(DD * FF);
#pragma unroll
  for (int im = 0; im < 4; ++im)
#pragma unroll
    for (int fn = 0; fn < 4; ++fn) {
      int f = wnf * 64 + fn * 16 + lr;
#pragma unroll
      for (int r = 0; r < 4; ++r) {
        int d = wmd * 64 + im * 16 + lq * 4 + r;
        Sp[(size_t)d * FF + f] = (_Float16)acc[im][fn][r];
      }
    }
}

// ---------------- k3: prefix->Wf, suffix in-place over S (becomes Wr) ------
__global__ void prefix_kernel(_Float16* S_Wr, _Float16* __restrict__ Wf) {
  size_t idx = (size_t)blockIdx.x * 256 + threadIdx.x;
  int bh = (int)(idx >> 15);
  int df = (int)(idx & 32767);
  size_t base = (size_t)bh * NC * 32768 + df;
  float vals[NC];
#pragma unroll
  for (int c = 0; c < NC; ++c) vals[c] = (float)S_Wr[base + (size_t)c * 32768];
  float run = 0.f;
#pragma unroll
  for (int c = 0; c < NC; ++c) { Wf[base + (size_t)c * 32768] = (_Float16)run; run += vals[c]; }
  run = 0.f;
#pragma unroll
  for (int c = NC - 1; c >= 0; --c) { S_Wr[base + (size_t)c * 32768] = (_Float16)run; run += vals[c]; }
}

// ---------------- k4: fused phase-2 scan (full chunk per block) ----------------
__global__ __launch_bounds__(512, 2)
void scan_kernel(const _Float16* __restrict__ qp, const _Float16* __restrict__ kp,
                 const _Float16* __restrict__ vT, const _Float16* __restrict__ Wf,
                 const _Float16* __restrict__ Wr, float* __restrict__ out) {
  __shared__ __align__(16) _Float16 vt[128][136];
  __shared__ __align__(16) _Float16 P[128][136];
  int blk = blockIdx.x;
  int c = blk & 31, bh = blk >> 5;
  const _Float16* qpc = qp + ((size_t)bh * NSEQ + c * CHK) * FF;
  const _Float16* kpc = kp + ((size_t)bh * NSEQ + c * CHK) * FF;
  int tid = threadIdx.x, lane = tid & 63, wv = tid >> 6, lr = lane & 15, lq = lane >> 4;
  int wm = wv & 3, wn = wv >> 2;  // wm: 4x32 rows; wn: 2x64 (s-half in A, d-half in B)

  // aq: 16 frags (reused by phase A and inter), batched but bounded
  f16x8 aq[2][8];
#pragma unroll
  for (int im = 0; im < 2; ++im)
#pragma unroll
    for (int ks = 0; ks < 8; ++ks)
      aq[im][ks] = *(const f16x8*)&qpc[(size_t)(wm * 32 + im * 16 + lr) * FF + ks * 32 + lq * 8];
  // stage vt (b128, conflict-free)
#pragma unroll
  for (int it = 0; it < 4; ++it) {
    int flat = it * 512 + tid;
    int d = flat >> 4, sg = flat & 15;
    *(f16x8*)&vt[d][sg * 8] = *(const f16x8*)&vT[((size_t)bh * DD + d) * NSEQ + c * CHK + sg * 8];
  }
  // Phase A: P = qp.kp^T with bk double-buffer over j
  f16x8 bk[2][8];
#pragma unroll
  for (int ks = 0; ks < 8; ++ks)
    bk[0][ks] = *(const f16x8*)&kpc[(size_t)(wn * 64 + lr) * FF + ks * 32 + lq * 8];
  f32x4 pacc[2][4] = {};
#pragma unroll
  for (int j = 0; j < 4; ++j) {
    int cur = j & 1;
    if (j < 3)
#pragma unroll
      for (int ks = 0; ks < 8; ++ks)
        bk[cur ^ 1][ks] = *(const f16x8*)&kpc[(size_t)(wn * 64 + (j + 1) * 16 + lr) * FF + ks * 32 + lq * 8];
#pragma unroll
    for (int ks = 0; ks < 8; ++ks)
#pragma unroll
      for (int im = 0; im < 2; ++im)
        pacc[im][j] = MFMA16(aq[im][ks], bk[cur][ks], pacc[im][j]);
  }
#pragma unroll
  for (int im = 0; im < 2; ++im)
#pragma unroll
    for (int j = 0; j < 4; ++j)
#pragma unroll
      for (int r = 0; r < 4; ++r)
        P[wm * 32 + im * 16 + lq * 4 + r][wn * 64 + j * 16 + lr] = (_Float16)pacc[im][j][r];

  // prefetch W frags for jd=0 (before barrier: overlaps P writes)
  const _Float16* Wfc = Wf + ((size_t)bh * NC + c) * (size_t)(DD * FF);
  const _Float16* Wrc = Wr + ((size_t)bh * NC + c) * (size_t)(DD * FF);
  f16x8 bf[8], br[8];
#pragma unroll
  for (int ks = 0; ks < 8; ++ks) {
    int d = wn * 64 + lr;
    bf[ks] = *(const f16x8*)&Wfc[(size_t)d * FF + ks * 32 + lq * 8];
    br[ks] = *(const f16x8*)&Wrc[(size_t)d * FF + ks * 32 + lq * 8];
  }
  __syncthreads();

  // Phase B: inter (q.W) per d-group; W prefetch 1 group ahead; intra interleaved
  f32x4 af[2][4] = {}, ar[2][4] = {};
#pragma unroll
  for (int jd = 0; jd < 4; ++jd) {
#pragma unroll
    for (int ks = 0; ks < 8; ++ks)
#pragma unroll
      for (int im = 0; im < 2; ++im) {
        af[im][jd] = MFMA16(aq[im][ks], bf[ks], af[im][jd]);
        ar[im][jd] = MFMA16(aq[im][ks], br[ks], ar[im][jd]);
      }
    if (jd < 3)
#pragma unroll
      for (int ks = 0; ks < 8; ++ks) {
        int d = wn * 64 + (jd + 1) * 16 + lr;
        bf[ks] = *(const f16x8*)&Wfc[(size_t)d * FF + ks * 32 + lq * 8];
        br[ks] = *(const f16x8*)&Wrc[(size_t)d * FF + ks * 32 + lq * 8];
      }
    // intra k-step ks=jd (LDS-only; covers W prefetch latency)
    {
      int ks = jd;
      f16x8 bv[4];
#pragma unroll
      for (int jd2 = 0; jd2 < 4; ++jd2)
        bv[jd2] = *(const f16x8*)&vt[wn * 64 + jd2 * 16 + lr][ks * 32 + lq * 8];
#pragma unroll
      for (int im = 0; im < 2; ++im) {
        int irow = wm * 32 + im * 16 + lr;
        f16x8 p = *(const f16x8*)&P[irow][ks * 32 + lq * 8];
        f16x8 pf = p, pr = p;
#pragma unroll
        for (int jj = 0; jj < 8; ++jj) {
          int s = ks * 32 + lq * 8 + jj;
          pf[jj] = (s <= irow) ? p[jj] : (_Float16)0.0f;
          pr[jj] = (s >= irow) ? p[jj] : (_Float16)0.0f;
        }
#pragma unroll
        for (int jd2 = 0; jd2 < 4; ++jd2) {
          af[im][jd2] = MFMA16(pf, bv[jd2], af[im][jd2]);
          ar[im][jd2] = MFMA16(pr, bv[jd2], ar[im][jd2]);
        }
      }
    }
  }

  // epilogue
  float* oc = out + ((size_t)bh * NSEQ + c * CHK) * DD;
#pragma unroll
  for (int im = 0; im < 2; ++im)
#pragma unroll
    for (int jd = 0; jd < 4; ++jd) {
      int d = wn * 64 + jd * 16 + lr;
#pragma unroll
      for (int r = 0; r < 4; ++r) {
        int il = wm * 32 + im * 16 + lq * 4 + r;
        int gi = c * CHK + il;
        oc[(size_t)il * DD + d] = af[im][jd][r] / (float)(gi + 1) + ar[im][jd][r] / (float)(NSEQ - gi);
      }
    }
}

// ---------------- launcher ----------------
extern "C" void kernel_launch(void* const* d_in, const int* in_sizes, int n_in,
                              void* d_out, int out_size, void* d_ws, size_t ws_size,
                              hipStream_t stream) {
  const float* q  = (const float*)d_in[0];
  const float* k  = (const float*)d_in[1];
  const float* v  = (const float*)d_in[2];
  const float* w1 = (const float*)d_in[3];
  const float* b1 = (const float*)d_in[4];
  const float* w2 = (const float*)d_in[5];
  const float* b2 = (const float*)d_in[6];
  float* out = (float*)d_out;

  char* ws = (char*)d_ws;
  const size_t SZ = 50331648ull;  // 24*4096*256*2B
  _Float16* w1h = (_Float16*)(ws);
  _Float16* w2h = (_Float16*)(ws + 65536);
  _Float16* qp  = (_Float16*)(ws + 196608);
  _Float16* kp  = (_Float16*)(ws + 196608 + SZ);
  _Float16* kpT = (_Float16*)(ws + 196608 + 2 * SZ);  // reused as Wf after s_kernel
  _Float16* S   = (_Float16*)(ws + 196608 + 3 * SZ);  // reused in-place as Wr
  _Float16* vT  = (_Float16*)(ws + 196608 + 4 * SZ);  // 24MB
  _Float16* Wf  = kpT;
  _Float16* Wr  = S;

  prep_kernel<<<dim3(256), dim3(256), 0, stream>>>(w1, w2, w1h, w2h);
  vt_kernel<<<dim3(BH * NC), dim3(256), 0, stream>>>(v, vT);
  phi_kernel<<<dim3(2 * NROWS / 128), dim3(512), 0, stream>>>(q, k, b1, b2, w1h, w2h, qp, kp, kpT);
  s_kernel<<<dim3(BH * NC), dim3(512), 0, stream>>>(vT, kpT, S);
  prefix_kernel<<<dim3(BH * DD * FF / 256), dim3(256), 0, stream>>>(S, Wf);
  scan_kernel<<<dim3(BH * NC), dim3(512), 0, stream>>>(qp, kp, vT, Wf, Wr, out);
}